// Round 5
// baseline (699.398 us; speedup 1.0000x reference)
//
#include <hip/hip_runtime.h>
#include <hip/hip_bf16.h>

typedef __bf16  bf16x8 __attribute__((ext_vector_type(8)));
typedef float   f32x4  __attribute__((ext_vector_type(4)));
typedef short   s16x8  __attribute__((ext_vector_type(8)));
typedef int     i32x4  __attribute__((ext_vector_type(4)));

typedef const __attribute__((address_space(1))) void g_void;
typedef __attribute__((address_space(3))) void l_void;

__device__ __forceinline__ short f2b(float x) {
    __hip_bfloat16 h = __float2bfloat16(x);
    return __builtin_bit_cast(short, h);
}

// pack two floats to bf16 pair in one int (lo | hi<<16)
__device__ __forceinline__ int pk2(float lo, float hi) {
    return (int)(unsigned short)f2b(lo) | ((int)f2b(hi) << 16);
}

// fast GELU: tanh form via hardware exp2. gelu(v) = v*t/(t+1),
// t = exp2(K1*(v + 0.044715 v^3)), K1 = 2*log2(e)*0.7978845608.
__device__ __forceinline__ float fast_gelu(float v) {
    const float a = fminf(2.3022082f * (v + 0.044715f * v * v * v), 126.0f);
    const float t = exp2f(a);
    return v * t / (t + 1.0f);
}

__device__ __forceinline__ f32x4 mfma16(s16x8 a, s16x8 b, f32x4 c) {
    return __builtin_amdgcn_mfma_f32_16x16x32_bf16(
        __builtin_bit_cast(bf16x8, a), __builtin_bit_cast(bf16x8, b), c, 0, 0, 0);
}

#define S16(x) __builtin_bit_cast(s16x8, x)

// ---------------- transpose + fp32 -> bf16 :  src [R,C] f32 -> dst [C,R] bf16
__global__ __launch_bounds__(256) void transpose_bf16(
    const float* __restrict__ src, short* __restrict__ dst, int R, int C) {
    __shared__ float tile[32][33];
    src += (size_t)blockIdx.z * R * C;
    dst += (size_t)blockIdx.z * R * C;
    const int c0 = blockIdx.x * 32, r0 = blockIdx.y * 32;
    const int tx = threadIdx.x & 31, ty = threadIdx.x >> 5;
#pragma unroll
    for (int i = 0; i < 32; i += 8)
        tile[ty + i][tx] = src[(size_t)(r0 + ty + i) * C + c0 + tx];
    __syncthreads();
#pragma unroll
    for (int i = 0; i < 32; i += 8)
        dst[(size_t)(c0 + ty + i) * R + r0 + tx] = f2b(tile[tx][ty + i]);
}

// ---------------- concat q/k/v bias into [3072] f32
__global__ __launch_bounds__(256) void concat_bias(
    const float* __restrict__ bq, const float* __restrict__ bk,
    const float* __restrict__ bv, float* __restrict__ o) {
    int i = blockIdx.x * 256 + threadIdx.x;
    if (i < 1024)      o[i] = bq[i];
    else if (i < 2048) o[i] = bk[i - 1024];
    else if (i < 3072) o[i] = bv[i - 2048];
}

// ---------------- LayerNorm (D=1024) f32 in -> bf16 out. 1 block/row, 256 thr
__global__ __launch_bounds__(256) void ln_bf16(
    const float* __restrict__ x, const float* __restrict__ gamma,
    const float* __restrict__ beta, short* __restrict__ out) {
    __shared__ float red[8];
    const int row = blockIdx.x, tid = threadIdx.x;
    const float4 v = *(const float4*)(x + (size_t)row * 1024 + tid * 4);
    float s = v.x + v.y + v.z + v.w;
    float q = v.x * v.x + v.y * v.y + v.z * v.z + v.w * v.w;
#pragma unroll
    for (int off = 32; off > 0; off >>= 1) {
        s += __shfl_xor(s, off);
        q += __shfl_xor(q, off);
    }
    if ((tid & 63) == 0) { red[(tid >> 6) * 2] = s; red[(tid >> 6) * 2 + 1] = q; }
    __syncthreads();
    s = red[0] + red[2] + red[4] + red[6];
    q = red[1] + red[3] + red[5] + red[7];
    const float mu = s * (1.0f / 1024.0f);
    const float var = q * (1.0f / 1024.0f) - mu * mu;
    const float rs = rsqrtf(var + 1e-5f);
    const float4 g  = *(const float4*)(gamma + tid * 4);
    const float4 bt = *(const float4*)(beta + tid * 4);
    short4 o;
    o.x = f2b((v.x - mu) * rs * g.x + bt.x);
    o.y = f2b((v.y - mu) * rs * g.y + bt.y);
    o.z = f2b((v.z - mu) * rs * g.z + bt.z);
    o.w = f2b((v.w - mu) * rs * g.w + bt.w);
    *(short4*)(out + (size_t)row * 1024 + tid * 4) = o;
}

// ---------------- bf16 MFMA GEMM (128x128, 2-barrier) for narrow-N GEMMs.
// MODE 1: f32 = acc+bias+resid  MODE 2: bf16 gelu(acc+b)
template <int MODE, int SWZ>
__global__ __launch_bounds__(512) void gemm_bf16(
    const short* __restrict__ A, const short* __restrict__ Bt,
    const float* __restrict__ bias, const float* __restrict__ resid,
    float* __restrict__ outf, short* __restrict__ outb, short* __restrict__ vt,
    int M, int N, int K) {
    __shared__ __align__(16) short As[2 * 128 * 32];
    __shared__ __align__(16) short Bs[2 * 128 * 32];

    const int tid = threadIdx.x;
    const int wave = tid >> 6, lane = tid & 63;
    const int l16 = lane & 15, quad = lane >> 4;
    const int wm = wave & 3, wn = wave >> 2;   // 4 row-strips x 2 col-strips
    const int gx = gridDim.x;
    const int g = blockIdx.y * gx + blockIdx.x;
    const int xcd = g & 7, s = g >> 3;
    int m0, n0;
    if (SWZ == 0) {                            // N-band (requires gx % 8 == 0)
        const int nband = gx >> 3;
        const int sm = s / nband;
        const int sn = s - sm * nband;
        m0 = sm * 128;
        n0 = (xcd * nband + sn) * 128;
    } else {                                   // M-band (requires gy % 8 == 0)
        const int mband = gridDim.y >> 3;
        const int sm = s / gx;
        m0 = (xcd * mband + sm) * 128;
        n0 = (s - sm * gx) * 128;
    }
    const int lrow = lane >> 2;        // 0..15
    const int lcol = (lane & 3) * 8;   // 16B chunk within a 32-elem panel row

    f32x4 acc[2][4] = {};

    for (int kk = 0; kk < K; kk += 64) {
#pragma unroll
        for (int p = 0; p < 2; ++p) {        // 32-K panel
            const int r = wave * 16 + lrow;  // 8 waves x 16 rows = 128
            const short* ga = A + (size_t)(m0 + r) * K + kk + p * 32 + lcol;
            short* la = &As[p * 4096 + wave * 512];
            __builtin_amdgcn_global_load_lds((g_void*)ga, (l_void*)la, 16, 0, 0);
            const short* gb = Bt + (size_t)(n0 + r) * K + kk + p * 32 + lcol;
            short* lb = &Bs[p * 4096 + wave * 512];
            __builtin_amdgcn_global_load_lds((g_void*)gb, (l_void*)lb, 16, 0, 0);
        }
        __syncthreads();
#pragma unroll
        for (int p = 0; p < 2; ++p) {
            s16x8 a[2], b[4];
#pragma unroll
            for (int t = 0; t < 2; ++t)
                a[t] = *(const s16x8*)&As[p * 4096 + (wm * 32 + t * 16 + l16) * 32 + quad * 8];
#pragma unroll
            for (int t = 0; t < 4; ++t)
                b[t] = *(const s16x8*)&Bs[p * 4096 + (wn * 64 + t * 16 + l16) * 32 + quad * 8];
#pragma unroll
            for (int mt = 0; mt < 2; ++mt)
#pragma unroll
                for (int nt = 0; nt < 4; ++nt)
                    acc[mt][nt] = mfma16(a[mt], b[nt], acc[mt][nt]);
        }
        __syncthreads();
    }

#pragma unroll
    for (int mt = 0; mt < 2; ++mt) {
#pragma unroll
        for (int nt = 0; nt < 4; ++nt) {
            const int row = m0 + wm * 32 + mt * 16 + quad * 4;   // + r
            const int col = n0 + wn * 64 + nt * 16 + l16;
            const float bc = bias[col];
            float v[4];
#pragma unroll
            for (int r = 0; r < 4; ++r) v[r] = acc[mt][nt][r] + bc;

            if (MODE == 1) {
#pragma unroll
                for (int r = 0; r < 4; ++r) {
                    const size_t rr = (size_t)(row + r);
                    outf[rr * N + col] = v[r] + resid[rr * N + col];
                }
            } else {
#pragma unroll
                for (int r = 0; r < 4; ++r)
                    outb[(size_t)(row + r) * N + col] = f2b(fast_gelu(v[r]));
            }
        }
    }
}

// ======================= 256x256 GEMM v5: cross-phase read pipeline ==========
// The R1-R4 failure mode: every schedule confirmed ds_reads issued in the SAME
// phase -> exposed ~600cy LDS drain per phase with idle matrix pipe. v5 makes
// every wait confirm >=1-subphase-old ops (fragment ping-pong FA/FB at k-panel
// granularity):
//   K-tile T (buf X):  [entry: FA = T.p0 in flight (issued at T-1.S1)]
//   S0: issue 12 reads T.p1->FB(buf X); lgkmcnt(12) [confirms FA];
//       32 indep MFMA(FA)
//   S1: issue 12 reads (T+1).p0->FA(buf X^1); lgkmcnt(12) [confirms FB];
//       8 stages tile T+2 -> buf X (after FB confirm = WAR-safe);
//       32 MFMA(FB); advance ptrs; vmcnt(8) [confirms T+1 stages, issued a
//       full tile (~2400cy) ago]; barrier.
// No lgkmcnt(0)/vmcnt(0) in the loop. Tail tiles stage/read duplicate data
// (<=128B past A/B into adjacent workspace allocs - mapped, unused).

#define DSR(dst, b, o)                                                       \
    asm volatile("ds_read_b128 %0, %1 offset:" #o : "=v"(dst) : "v"(b))

#define LGKM12                                                               \
    asm volatile("s_waitcnt lgkmcnt(12)" ::: "memory");                      \
    __builtin_amdgcn_sched_barrier(0)

#define MM32(A, B)                                                           \
    acc[0][0]=mfma16(S16(A##0),S16(B##0),acc[0][0]);                         \
    acc[0][1]=mfma16(S16(A##0),S16(B##1),acc[0][1]);                         \
    acc[0][2]=mfma16(S16(A##0),S16(B##2),acc[0][2]);                         \
    acc[0][3]=mfma16(S16(A##0),S16(B##3),acc[0][3]);                         \
    acc[1][0]=mfma16(S16(A##1),S16(B##0),acc[1][0]);                         \
    acc[1][1]=mfma16(S16(A##1),S16(B##1),acc[1][1]);                         \
    acc[1][2]=mfma16(S16(A##1),S16(B##2),acc[1][2]);                         \
    acc[1][3]=mfma16(S16(A##1),S16(B##3),acc[1][3]);                         \
    acc[2][0]=mfma16(S16(A##2),S16(B##0),acc[2][0]);                         \
    acc[2][1]=mfma16(S16(A##2),S16(B##1),acc[2][1]);                         \
    acc[2][2]=mfma16(S16(A##2),S16(B##2),acc[2][2]);                         \
    acc[2][3]=mfma16(S16(A##2),S16(B##3),acc[2][3]);                         \
    acc[3][0]=mfma16(S16(A##3),S16(B##0),acc[3][0]);                         \
    acc[3][1]=mfma16(S16(A##3),S16(B##1),acc[3][1]);                         \
    acc[3][2]=mfma16(S16(A##3),S16(B##2),acc[3][2]);                         \
    acc[3][3]=mfma16(S16(A##3),S16(B##3),acc[3][3]);                         \
    acc[4][0]=mfma16(S16(A##4),S16(B##0),acc[4][0]);                         \
    acc[4][1]=mfma16(S16(A##4),S16(B##1),acc[4][1]);                         \
    acc[4][2]=mfma16(S16(A##4),S16(B##2),acc[4][2]);                         \
    acc[4][3]=mfma16(S16(A##4),S16(B##3),acc[4][3]);                         \
    acc[5][0]=mfma16(S16(A##5),S16(B##0),acc[5][0]);                         \
    acc[5][1]=mfma16(S16(A##5),S16(B##1),acc[5][1]);                         \
    acc[5][2]=mfma16(S16(A##5),S16(B##2),acc[5][2]);                         \
    acc[5][3]=mfma16(S16(A##5),S16(B##3),acc[5][3]);                         \
    acc[6][0]=mfma16(S16(A##6),S16(B##0),acc[6][0]);                         \
    acc[6][1]=mfma16(S16(A##6),S16(B##1),acc[6][1]);                         \
    acc[6][2]=mfma16(S16(A##6),S16(B##2),acc[6][2]);                         \
    acc[6][3]=mfma16(S16(A##6),S16(B##3),acc[6][3]);                         \
    acc[7][0]=mfma16(S16(A##7),S16(B##0),acc[7][0]);                         \
    acc[7][1]=mfma16(S16(A##7),S16(B##1),acc[7][1]);                         \
    acc[7][2]=mfma16(S16(A##7),S16(B##2),acc[7][2]);                         \
    acc[7][3]=mfma16(S16(A##7),S16(B##3),acc[7][3])

// panel-0 reads (offsets (2i)*1024 B) into set S from bases AR/BR
#define READ_P0(SA, SB, AR, BR)                                              \
    DSR(SB##0, BR, 0);    DSR(SB##1, BR, 2048);                              \
    DSR(SB##2, BR, 4096); DSR(SB##3, BR, 6144);                              \
    DSR(SA##0, AR, 0);    DSR(SA##1, AR, 2048);                              \
    DSR(SA##2, AR, 4096); DSR(SA##3, AR, 6144);                              \
    DSR(SA##4, AR, 8192); DSR(SA##5, AR, 10240);                             \
    DSR(SA##6, AR, 12288); DSR(SA##7, AR, 14336)

// panel-1 reads (offsets (2i+1)*1024 B)
#define READ_P1(SA, SB, AR, BR)                                              \
    DSR(SB##0, BR, 1024); DSR(SB##1, BR, 3072);                              \
    DSR(SB##2, BR, 5120); DSR(SB##3, BR, 7168);                              \
    DSR(SA##0, AR, 1024); DSR(SA##1, AR, 3072);                              \
    DSR(SA##2, AR, 5120); DSR(SA##3, AR, 7168);                              \
    DSR(SA##4, AR, 9216); DSR(SA##5, AR, 11264);                             \
    DSR(SA##6, AR, 13312); DSR(SA##7, AR, 15360)

// one K-tile: cur buf read bases ARc/BRc, next buf ARn/BRn, stage->BUFB bytes
#define TILE(ARc, BRc, ARn, BRn, BUFB)                                       \
    READ_P1(ga, gb, ARc, BRc);                                               \
    LGKM12;                                                                  \
    __builtin_amdgcn_s_setprio(1);                                           \
    MM32(fa, fb);                                                            \
    __builtin_amdgcn_s_setprio(0);                                           \
    __builtin_amdgcn_sched_barrier(0);                                       \
    READ_P0(fa, fb, ARn, BRn);                                               \
    LGKM12;                                                                  \
    STAGE8(BUFB);                                                            \
    __builtin_amdgcn_s_setprio(1);                                           \
    MM32(ga, gb);                                                            \
    __builtin_amdgcn_s_setprio(0);                                           \
    __builtin_amdgcn_sched_barrier(0);                                       \
    ADV();                                                                   \
    asm volatile("s_waitcnt vmcnt(8)" ::: "memory");                         \
    __builtin_amdgcn_s_barrier();                                            \
    __builtin_amdgcn_sched_barrier(0)

// MODE 0: QKV scatter (Q pre-scaled, K -> [2][B,H,S,HD], V -> vt [B,H,HD,S])
// MODE 1: out f32 = acc + bias[col] + resid   MODE 2: out bf16 = gelu(acc+b)
template <int MODE>
__global__ __launch_bounds__(512, 2) void gemm256(
    const short* __restrict__ A, const short* __restrict__ Bt,
    const float* __restrict__ bias, const float* __restrict__ resid,
    float* __restrict__ outf, short* __restrict__ outb, short* __restrict__ vt,
    int M, int N, int K) {
    __shared__ __align__(16) short As[32768];   // 2 bufs x 2 halves x 8192
    __shared__ __align__(16) short Bs[32768];

    const int tid = threadIdx.x;
    const int wave = tid >> 6, lane = tid & 63;
    const int l16 = lane & 15, quad = lane >> 4;
    const int wm = wave >> 2, wn = wave & 3;    // 2 x 4 wave grid

    // XCD-chunked bijective swizzle (gridDim.x % 8 == 0), m-fastest order.
    const int nwg = gridDim.x;
    const int g = blockIdx.x;
    const int wgid = (g & 7) * (nwg >> 3) + (g >> 3);
    const int mtiles = M >> 8;
    const int m0 = (wgid % mtiles) << 8;
    const int n0 = (wgid / mtiles) << 8;

    // ---- read-side swizzled offsets (shorts) -> 32-bit LDS byte addresses
    const int rc = l16 * 32 + ((quad * 8) ^ ((l16 >> 3) << 4));
    const int a_rd = wm * 8192 + rc;
    const int b_rd = (wn >> 1) * 8192 + (wn & 1) * 4096 + rc;

    const uint32_t asb = (uint32_t)(uintptr_t)(l_void*)&As[0];
    const uint32_t bsb = (uint32_t)(uintptr_t)(l_void*)&Bs[0];
    const uint32_t aRd0 = asb + 2u * (uint32_t)a_rd, aRd1 = aRd0 + 32768u;
    const uint32_t bRd0 = bsb + 2u * (uint32_t)b_rd, bRd1 = bRd0 + 32768u;

    // ---- stage-side inverse swizzle: linear chunk s=tid*16 bytes holds (r,c)
    int r0, c0, r1, c1;
    {
        int s = tid * 16;
        int lin = s ^ (((s >> 9) & 1) << 5);
        r0 = ((lin >> 11) << 4) + ((lin >> 6) & 15);
        c0 = (((lin >> 10) & 1) << 5) + ((lin & 63) >> 1);
        s = (tid + 512) * 16;
        lin = s ^ (((s >> 9) & 1) << 5);
        r1 = ((lin >> 11) << 4) + ((lin >> 6) & 15);
        c1 = (((lin >> 10) & 1) << 5) + ((lin & 63) >> 1);
    }

    // 8 per-thread global stage pointers (advance +64 shorts per tile)
    const short* pa00 = A + (size_t)(m0 + r0) * K + c0;         // A h0, d0
    const short* pa01 = A + (size_t)(m0 + r1) * K + c1;         // A h0, d1
    const short* pa10 = A + (size_t)(m0 + 128 + r0) * K + c0;   // A h1, d0
    const short* pa11 = A + (size_t)(m0 + 128 + r1) * K + c1;   // A h1, d1
    const short* pb00 = Bt + (size_t)(n0 + r0) * K + c0;
    const short* pb01 = Bt + (size_t)(n0 + r1) * K + c1;
    const short* pb10 = Bt + (size_t)(n0 + 128 + r0) * K + c0;
    const short* pb11 = Bt + (size_t)(n0 + 128 + r1) * K + c1;

    short* lA = &As[0];
    short* lB = &Bs[0];
    const int wv512 = wave * 512;   // shorts

    auto STAGE8 = [&](int bufsh) {   // bufsh: buffer offset in shorts
        __builtin_amdgcn_global_load_lds((g_void*)pa00, (l_void*)(lA + bufsh + wv512), 16, 0, 0);
        __builtin_amdgcn_global_load_lds((g_void*)pa01, (l_void*)(lA + bufsh + 4096 + wv512), 16, 0, 0);
        __builtin_amdgcn_global_load_lds((g_void*)pa10, (l_void*)(lA + bufsh + 8192 + wv512), 16, 0, 0);
        __builtin_amdgcn_global_load_lds((g_void*)pa11, (l_void*)(lA + bufsh + 12288 + wv512), 16, 0, 0);
        __builtin_amdgcn_global_load_lds((g_void*)pb00, (l_void*)(lB + bufsh + wv512), 16, 0, 0);
        __builtin_amdgcn_global_load_lds((g_void*)pb01, (l_void*)(lB + bufsh + 4096 + wv512), 16, 0, 0);
        __builtin_amdgcn_global_load_lds((g_void*)pb10, (l_void*)(lB + bufsh + 8192 + wv512), 16, 0, 0);
        __builtin_amdgcn_global_load_lds((g_void*)pb11, (l_void*)(lB + bufsh + 12288 + wv512), 16, 0, 0);
    };
    auto ADV = [&]() {
        pa00 += 64; pa01 += 64; pa10 += 64; pa11 += 64;
        pb00 += 64; pb01 += 64; pb10 += 64; pb11 += 64;
    };

    f32x4 acc[8][4] = {};
    i32x4 fa0, fa1, fa2, fa3, fa4, fa5, fa6, fa7, fb0, fb1, fb2, fb3;
    i32x4 ga0, ga1, ga2, ga3, ga4, ga5, ga6, ga7, gb0, gb1, gb2, gb3;

    // prologue: stage tile0->buf0, tile1->buf1; full confirm; read T0.p0->FA
    STAGE8(0);      ADV();
    STAGE8(16384);  ADV();           // pointers now at tile 2
    asm volatile("s_waitcnt vmcnt(0)" ::: "memory");
    __builtin_amdgcn_s_barrier();
    __builtin_amdgcn_sched_barrier(0);
    READ_P0(fa, fb, aRd0, bRd0);

    const int NT = K >> 6;           // even (K multiple of 128)
    for (int it = 0; it < NT; it += 2) {
        TILE(aRd0, bRd0, aRd1, bRd1, 0);       // even tile: buf0
        TILE(aRd1, bRd1, aRd0, bRd0, 16384);   // odd tile:  buf1
    }
    asm volatile("s_waitcnt vmcnt(0) lgkmcnt(0)" ::: "memory");

    // ---- epilogue
#pragma unroll
    for (int i = 0; i < 8; ++i) {
#pragma unroll
        for (int j = 0; j < 4; ++j) {
            const int row = m0 + wm * 128 + i * 16 + quad * 4;   // + r
            const int col = n0 + wn * 64 + j * 16 + l16;
            const float bc = bias[col];
            float v[4];
#pragma unroll
            for (int r = 0; r < 4; ++r) v[r] = acc[i][j][r] + bc;

            if (MODE == 0) {
                const int sel = col >> 10, within = col & 1023;
                const int h = within >> 6, hd = within & 63;
                const size_t bidx = (size_t)row >> 11, sp = row & 2047;
                if (sel == 0) {
                    // fold softmax scale (1/sqrt(64) * log2e) into Q
#pragma unroll
                    for (int r = 0; r < 4; ++r) v[r] *= 0.18033688011112042f;
                }
                if (sel < 2) {
#pragma unroll
                    for (int r = 0; r < 4; ++r)
                        outb[(size_t)sel * (8192ull * 1024) +
                             ((bidx * 16 + h) * 2048 + sp + r) * 64 + hd] = f2b(v[r]);
                } else {
                    short4 o4;
                    o4.x = f2b(v[0]); o4.y = f2b(v[1]);
                    o4.z = f2b(v[2]); o4.w = f2b(v[3]);
                    *(short4*)&vt[((bidx * 16 + h) * 64 + hd) * 2048 + sp] = o4;
                }
            } else if (MODE == 1) {
#pragma unroll
                for (int r = 0; r < 4; ++r) {
                    const size_t rr = (size_t)(row + r);
                    outf[rr * N + col] = v[r] + resid[rr * N + col];
                }
            } else {
#pragma unroll
                for (int r = 0; r < 4; ++r)
                    outb[(size_t)(row + r) * N + col] = f2b(fast_gelu(v[r]));
            }
        }
    }
}

#undef TILE
#undef READ_P0
#undef READ_P1
#undef MM32
#undef LGKM12
#undef DSR

// ---------------- causal flash attention v4: S^T formulation, no-max softmax,
// double-buffered K/V (one barrier/iter), XCD-affinity block mapping.
__global__ __launch_bounds__(256) void attn_kernel(
    const short* __restrict__ Q, const short* __restrict__ K,
    const short* __restrict__ Vt, short* __restrict__ O) {
    const int bid = blockIdx.x;
    const int xcd = bid & 7;
    const int sub = (bid >> 3) & 7;    // gq
    const int grp = bid >> 6;          // 0..7
    const int bh  = grp * 8 + xcd;     // bh % 8 == xcd
    const int h = bh & 15, b = bh >> 4;
    const int gq = sub;
    const int tid = threadIdx.x, wave = tid >> 6, lane = tid & 63;
    const int l16 = lane & 15, quad = lane >> 4;

    __shared__ __align__(16) short Ks[2][64 * 72];
    __shared__ __align__(16) short Vts[2][64 * 72];
    __shared__ __align__(16) short Ps[4][16 * 72];

    const size_t bhoff = (size_t)bh * (2048ull * 64);
    const int srow = tid >> 2;
    const int sseg = (tid & 3) * 16;

    const int qts[4] = {gq, 15 - gq, 16 + gq, 31 - gq};

    for (int pass = 0; pass < 4; ++pass) {
        const int qt = qts[pass];
        const int q0 = qt * 64;
        const int q_lane = q0 + wave * 16 + l16;

        const short* qrow = Q + bhoff + (size_t)q_lane * 64;
        s16x8 bq0 = *(const s16x8*)(qrow + quad * 8);
        s16x8 bq1 = *(const s16x8*)(qrow + 32 + quad * 8);

        f32x4 oacc[4] = {};
        float lsum = 0.0f;

        // prologue: load j=0 tile
        s16x8 k0, k1, v0, v1;
        {
            const short* kg = K + bhoff + (size_t)srow * 64 + sseg;
            k0 = *(const s16x8*)kg;
            k1 = *(const s16x8*)(kg + 8);
            const short* vg = Vt + bhoff + (size_t)srow * 2048 + sseg;
            v0 = *(const s16x8*)vg;
            v1 = *(const s16x8*)(vg + 8);
        }

        for (int j = 0; j <= qt; ++j) {
            const int buf = j & 1;
            *(s16x8*)&Ks[buf][srow * 72 + sseg]      = k0;
            *(s16x8*)&Ks[buf][srow * 72 + sseg + 8]  = k1;
            *(s16x8*)&Vts[buf][srow * 72 + sseg]     = v0;
            *(s16x8*)&Vts[buf][srow * 72 + sseg + 8] = v1;
            __syncthreads();

            if (j < qt) {
                const short* kg = K + bhoff + (size_t)((j + 1) * 64 + srow) * 64 + sseg;
                k0 = *(const s16x8*)kg;
                k1 = *(const s16x8*)(kg + 8);
                const short* vg = Vt + bhoff + (size_t)srow * 2048 + (j + 1) * 64 + sseg;
                v0 = *(const s16x8*)vg;
                v1 = *(const s16x8*)(vg + 8);
            }

            f32x4 st[4];
#pragma unroll
            for (int s = 0; s < 4; ++s) {
                s16x8 ak0 = *(const s16x8*)&Ks[buf][(s * 16 + l16) * 72 + quad * 8];
                s16x8 ak1 = *(const s16x8*)&Ks[buf][(s * 16 + l16) * 72 + 32 + quad * 8];
                f32x4 c = {};
                c = mfma16(ak0, bq0, c);
                c = mfma16(ak1, bq1, c);
                st[s] = c;
            }
            if (j == qt) {
#pragma unroll
                for (int s = 0; s < 4; ++s)
#pragma unroll
                    for (int r = 0; r < 4; ++r) {
                        const int t = j * 64 + s * 16 + quad * 4 + r;
                        if (t > q_lane) st[s][r] = -3000.0f;
                    }
            }
            float rs = 0.0f;
#pragma unroll
            for (int s = 0; s < 4; ++s) {
#pragma unroll
                for (int r = 0; r < 4; ++r) {
                    st[s][r] = exp2f(st[s][r]);
                    rs += st[s][r];
                }
                int2 pw;
                pw.x = pk2(st[s][0], st[s][1]);
                pw.y = pk2(st[s][2], st[s][3]);
                *(int2*)&Ps[wave][l16 * 72 + s * 16 + quad * 4] = pw;
            }
            rs += __shfl_xor(rs, 16);
            rs += __shfl_xor(rs, 32);
            lsum += rs;

            asm volatile("s_waitcnt lgkmcnt(0)" ::: "memory");
            s16x8 ap0 = *(const s16x8*)&Ps[wave][l16 * 72 + quad * 8];
            s16x8 ap1 = *(const s16x8*)&Ps[wave][l16 * 72 + 32 + quad * 8];

#pragma unroll
            for (int nt = 0; nt < 4; ++nt) {
                s16x8 bv0 = *(const s16x8*)&Vts[buf][(nt * 16 + l16) * 72 + quad * 8];
                s16x8 bv1 = *(const s16x8*)&Vts[buf][(nt * 16 + l16) * 72 + 32 + quad * 8];
                oacc[nt] = mfma16(ap0, bv0, oacc[nt]);
                oacc[nt] = mfma16(ap1, bv1, oacc[nt]);
            }
        }
        __syncthreads();

        float inv[4];
#pragma unroll
        for (int r = 0; r < 4; ++r)
            inv[r] = 1.0f / __shfl(lsum, quad * 4 + r, 64);
#pragma unroll
        for (int nt = 0; nt < 4; ++nt)
#pragma unroll
            for (int r = 0; r < 4; ++r) {
                const int row = q0 + wave * 16 + quad * 4 + r;
                O[((size_t)b * 2048 + row) * 1024 + h * 64 + nt * 16 + l16] =
                    f2b(oacc[nt][r] * inv[r]);
            }
    }
}

extern "C" void kernel_launch(void* const* d_in, const int* in_sizes, int n_in,
                              void* d_out, int out_size, void* d_ws, size_t ws_size,
                              hipStream_t stream) {
    const float* x     = (const float*)d_in[0];
    const float* Wq    = (const float*)d_in[1];
    const float* Wk    = (const float*)d_in[2];
    const float* Wv    = (const float*)d_in[3];
    const float* bq    = (const float*)d_in[4];
    const float* bk    = (const float*)d_in[5];
    const float* bv    = (const float*)d_in[6];
    const float* Wo    = (const float*)d_in[7];
    const float* bo    = (const float*)d_in[8];
    const float* W1    = (const float*)d_in[9];
    const float* b1    = (const float*)d_in[10];
    const float* W2    = (const float*)d_in[11];
    const float* b2    = (const float*)d_in[12];
    const float* gamma = (const float*)d_in[13];
    const float* beta  = (const float*)d_in[14];
    float* out = (float*)d_out;

    char* ws = (char*)d_ws;
    size_t off = 0;
    auto alloc = [&](size_t bytes) -> char* {
        char* p = ws + off;
        off += (bytes + 255) & ~(size_t)255;
        return p;
    };
    short* h1    = (short*)alloc(8192ull * 1024 * 2);
    short* btqkv = (short*)alloc(3072ull * 1024 * 2);
    short* btwo  = (short*)alloc(1024ull * 1024 * 2);
    short* btw1  = (short*)alloc(4096ull * 1024 * 2);
    short* btw2  = (short*)alloc(1024ull * 4096 * 2);
    float* bqkv  = (float*)alloc(3072ull * 4);
    short* qkv   = (short*)alloc(2ull * 8192 * 1024 * 2);   // Q,K only
    short* vt    = (short*)alloc(8192ull * 1024 * 2);       // V pre-transposed
    short* aout  = (short*)alloc(8192ull * 1024 * 2);
    float* x2    = (float*)alloc(8192ull * 1024 * 4);
    short* h2    = (short*)alloc(8192ull * 1024 * 2);
    short* m1    = (short*)alloc(8192ull * 4096 * 2);

    // weight prep
    transpose_bf16<<<dim3(2, 32, 16), 256, 0, stream>>>(Wq, btqkv, 1024, 64);
    transpose_bf16<<<dim3(2, 32, 16), 256, 0, stream>>>(Wk, btqkv + 1024ull * 1024, 1024, 64);
    transpose_bf16<<<dim3(2, 32, 16), 256, 0, stream>>>(Wv, btqkv + 2ull * 1024 * 1024, 1024, 64);
    transpose_bf16<<<dim3(32, 32, 1), 256, 0, stream>>>(Wo, btwo, 1024, 1024);
    transpose_bf16<<<dim3(128, 32, 1), 256, 0, stream>>>(W1, btw1, 1024, 4096);
    transpose_bf16<<<dim3(32, 128, 1), 256, 0, stream>>>(W2, btw2, 4096, 1024);
    concat_bias<<<12, 256, 0, stream>>>(bq, bk, bv, bqkv);

    // LN1
    ln_bf16<<<8192, 256, 0, stream>>>(x, gamma, beta, h1);
    // QKV projection: 256^2 v5 (32 m-tiles x 12 n-tiles)
    gemm256<0><<<384, 512, 0, stream>>>(
        h1, btqkv, bqkv, nullptr, nullptr, qkv, vt, 8192, 3072, 1024);
    // attention (XCD-affinity mapping)
    attn_kernel<<<512, 256, 0, stream>>>(
        qkv, qkv + 8192ull * 1024, vt, aout);
    // Wo + residual -> x2 (f32): narrow-N, 128^2 kernel
    gemm_bf16<1, 0><<<dim3(8, 64), 512, 0, stream>>>(
        aout, btwo, bo, x, x2, nullptr, nullptr, 8192, 1024, 1024);
    // LN2
    ln_bf16<<<8192, 256, 0, stream>>>(x2, gamma, beta, h2);
    // MLP1 + GELU: 256^2 v5 (32 x 16 = 512 blocks, 2/CU rounds)
    gemm256<2><<<512, 512, 0, stream>>>(
        h2, btw1, b1, nullptr, nullptr, m1, nullptr, 8192, 4096, 1024);
    // MLP2 + residual -> out (f32), narrow-N long-K: 128^2 M-band kernel
    gemm_bf16<1, 1><<<dim3(8, 64), 512, 0, stream>>>(
        m1, btw2, b2, x2, out, nullptr, nullptr, 8192, 1024, 4096);
}

// Round 6
// 520.232 us; speedup vs baseline: 1.3444x; 1.3444x over previous
//
#include <hip/hip_runtime.h>
#include <hip/hip_bf16.h>

typedef __bf16  bf16x8 __attribute__((ext_vector_type(8)));
typedef float   f32x4  __attribute__((ext_vector_type(4)));
typedef short   s16x8  __attribute__((ext_vector_type(8)));

typedef const __attribute__((address_space(1))) void g_void;
typedef __attribute__((address_space(3))) void l_void;

__device__ __forceinline__ short f2b(float x) {
    __hip_bfloat16 h = __float2bfloat16(x);
    return __builtin_bit_cast(short, h);
}

// pack two floats to bf16 pair in one int (lo | hi<<16)
__device__ __forceinline__ int pk2(float lo, float hi) {
    return (int)(unsigned short)f2b(lo) | ((int)f2b(hi) << 16);
}

// fast GELU: tanh form via hardware exp2. gelu(v) = v*t/(t+1),
// t = exp2(K1*(v + 0.044715 v^3)), K1 = 2*log2(e)*0.7978845608.
__device__ __forceinline__ float fast_gelu(float v) {
    const float a = fminf(2.3022082f * (v + 0.044715f * v * v * v), 126.0f);
    const float t = exp2f(a);
    return v * t / (t + 1.0f);
}

__device__ __forceinline__ f32x4 mfma16(s16x8 a, s16x8 b, f32x4 c) {
    return __builtin_amdgcn_mfma_f32_16x16x32_bf16(
        __builtin_bit_cast(bf16x8, a), __builtin_bit_cast(bf16x8, b), c, 0, 0, 0);
}

// ---------------- transpose + fp32 -> bf16 :  src [R,C] f32 -> dst [C,R] bf16
__global__ __launch_bounds__(256) void transpose_bf16(
    const float* __restrict__ src, short* __restrict__ dst, int R, int C) {
    __shared__ float tile[32][33];
    src += (size_t)blockIdx.z * R * C;
    dst += (size_t)blockIdx.z * R * C;
    const int c0 = blockIdx.x * 32, r0 = blockIdx.y * 32;
    const int tx = threadIdx.x & 31, ty = threadIdx.x >> 5;
#pragma unroll
    for (int i = 0; i < 32; i += 8)
        tile[ty + i][tx] = src[(size_t)(r0 + ty + i) * C + c0 + tx];
    __syncthreads();
#pragma unroll
    for (int i = 0; i < 32; i += 8)
        dst[(size_t)(c0 + ty + i) * R + r0 + tx] = f2b(tile[tx][ty + i]);
}

// ---------------- concat q/k/v bias into [3072] f32
__global__ __launch_bounds__(256) void concat_bias(
    const float* __restrict__ bq, const float* __restrict__ bk,
    const float* __restrict__ bv, float* __restrict__ o) {
    int i = blockIdx.x * 256 + threadIdx.x;
    if (i < 1024)      o[i] = bq[i];
    else if (i < 2048) o[i] = bk[i - 1024];
    else if (i < 3072) o[i] = bv[i - 2048];
}

// ---------------- LayerNorm (D=1024) f32 in -> bf16 out. 1 block/row, 256 thr
__global__ __launch_bounds__(256) void ln_bf16(
    const float* __restrict__ x, const float* __restrict__ gamma,
    const float* __restrict__ beta, short* __restrict__ out) {
    __shared__ float red[8];
    const int row = blockIdx.x, tid = threadIdx.x;
    const float4 v = *(const float4*)(x + (size_t)row * 1024 + tid * 4);
    float s = v.x + v.y + v.z + v.w;
    float q = v.x * v.x + v.y * v.y + v.z * v.z + v.w * v.w;
#pragma unroll
    for (int off = 32; off > 0; off >>= 1) {
        s += __shfl_xor(s, off);
        q += __shfl_xor(q, off);
    }
    if ((tid & 63) == 0) { red[(tid >> 6) * 2] = s; red[(tid >> 6) * 2 + 1] = q; }
    __syncthreads();
    s = red[0] + red[2] + red[4] + red[6];
    q = red[1] + red[3] + red[5] + red[7];
    const float mu = s * (1.0f / 1024.0f);
    const float var = q * (1.0f / 1024.0f) - mu * mu;
    const float rs = rsqrtf(var + 1e-5f);
    const float4 g  = *(const float4*)(gamma + tid * 4);
    const float4 bt = *(const float4*)(beta + tid * 4);
    short4 o;
    o.x = f2b((v.x - mu) * rs * g.x + bt.x);
    o.y = f2b((v.y - mu) * rs * g.y + bt.y);
    o.z = f2b((v.z - mu) * rs * g.z + bt.z);
    o.w = f2b((v.w - mu) * rs * g.w + bt.w);
    *(short4*)(out + (size_t)row * 1024 + tid * 4) = o;
}

// ---------------- bf16 MFMA GEMM: C[M,N] = A[M,K] * Bt[N,K]^T (+ epilogue)
// 128x128 tile, BK=64 as two 32-K panels, 512 threads (8 waves).
// SWZ 0 (N-band): each XCD owns an N-band whose B-slice stays L2-resident.
// SWZ 1 (M-band): each XCD owns a contiguous M-band (best for MLP2, R8).
// MODE 0: Q/K scatter (N=2048): Q (pre-scaled by 1/8*log2e), K -> [2][B,H,S,HD]
// MODE 1: out f32 = acc + bias[col] + resid[row*N+col]
// MODE 2: out bf16 = fast_gelu(acc + bias[col])
// MODE 3: out bf16 = acc + bias[row]  (row-indexed bias; used for V^T GEMM)
template <int MODE, int SWZ>
__global__ __launch_bounds__(512) void gemm_bf16(
    const short* __restrict__ A, const short* __restrict__ Bt,
    const float* __restrict__ bias, const float* __restrict__ resid,
    float* __restrict__ outf, short* __restrict__ outb,
    int M, int N, int K) {
    __shared__ __align__(16) short As[2 * 128 * 32];
    __shared__ __align__(16) short Bs[2 * 128 * 32];

    const int tid = threadIdx.x;
    const int wave = tid >> 6, lane = tid & 63;
    const int l16 = lane & 15, quad = lane >> 4;
    const int wm = wave & 3, wn = wave >> 2;   // 4 row-strips x 2 col-strips
    const int gx = gridDim.x;
    const int g = blockIdx.y * gx + blockIdx.x;
    const int xcd = g & 7, s = g >> 3;
    int m0, n0;
    if (SWZ == 0) {                            // N-band (requires gx % 8 == 0)
        const int nband = gx >> 3;
        const int sm = s / nband;
        const int sn = s - sm * nband;
        m0 = sm * 128;
        n0 = (xcd * nband + sn) * 128;
    } else {                                   // M-band (requires gy % 8 == 0)
        const int mband = gridDim.y >> 3;
        const int sm = s / gx;
        m0 = (xcd * mband + sm) * 128;
        n0 = (s - sm * gx) * 128;
    }
    const int lrow = lane >> 2;        // 0..15
    const int lcol = (lane & 3) * 8;   // 16B chunk within a 32-elem panel row

    f32x4 acc[2][4] = {};

    for (int kk = 0; kk < K; kk += 64) {
#pragma unroll
        for (int p = 0; p < 2; ++p) {        // 32-K panel
            const int r = wave * 16 + lrow;  // 8 waves x 16 rows = 128
            const short* ga = A + (size_t)(m0 + r) * K + kk + p * 32 + lcol;
            short* la = &As[p * 4096 + wave * 512];
            __builtin_amdgcn_global_load_lds((g_void*)ga, (l_void*)la, 16, 0, 0);
            const short* gb = Bt + (size_t)(n0 + r) * K + kk + p * 32 + lcol;
            short* lb = &Bs[p * 4096 + wave * 512];
            __builtin_amdgcn_global_load_lds((g_void*)gb, (l_void*)lb, 16, 0, 0);
        }
        __syncthreads();
#pragma unroll
        for (int p = 0; p < 2; ++p) {
            s16x8 a[2], b[4];
#pragma unroll
            for (int t = 0; t < 2; ++t)
                a[t] = *(const s16x8*)&As[p * 4096 + (wm * 32 + t * 16 + l16) * 32 + quad * 8];
#pragma unroll
            for (int t = 0; t < 4; ++t)
                b[t] = *(const s16x8*)&Bs[p * 4096 + (wn * 64 + t * 16 + l16) * 32 + quad * 8];
#pragma unroll
            for (int mt = 0; mt < 2; ++mt)
#pragma unroll
                for (int nt = 0; nt < 4; ++nt)
                    acc[mt][nt] = mfma16(a[mt], b[nt], acc[mt][nt]);
        }
        __syncthreads();
    }

#pragma unroll
    for (int mt = 0; mt < 2; ++mt) {
#pragma unroll
        for (int nt = 0; nt < 4; ++nt) {
            const int row = m0 + wm * 32 + mt * 16 + quad * 4;   // + r
            const int col = n0 + wn * 64 + nt * 16 + l16;
            // MODE 3 bias is row-indexed (bias has M entries, col spans N)
            const float bc = (MODE == 3) ? 0.0f : bias[col];
            float v[4];
#pragma unroll
            for (int r = 0; r < 4; ++r) v[r] = acc[mt][nt][r] + bc;

            if (MODE == 0) {
                // N=2048: sel in {0,1} (Q,K). V handled by the MODE-3 GEMM.
                const int sel = col >> 10, within = col & 1023;
                const int h = within >> 6, hd = within & 63;
                const size_t bidx = (size_t)row >> 11, sp = row & 2047;
                if (sel == 0) {
                    // fold softmax scale (1/sqrt(64) * log2e) into Q
#pragma unroll
                    for (int r = 0; r < 4; ++r) v[r] *= 0.18033688011112042f;
                }
#pragma unroll
                for (int r = 0; r < 4; ++r)
                    outb[(size_t)sel * (8192ull * 1024) +
                         ((bidx * 16 + h) * 2048 + sp + r) * 64 + hd] = f2b(v[r]);
            } else if (MODE == 1) {
#pragma unroll
                for (int r = 0; r < 4; ++r) {
                    const size_t rr = (size_t)(row + r);
                    outf[rr * N + col] = v[r] + resid[rr * N + col];
                }
            } else if (MODE == 2) {
#pragma unroll
                for (int r = 0; r < 4; ++r)
                    outb[(size_t)(row + r) * N + col] = f2b(fast_gelu(v[r]));
            } else {
                // MODE 3: natural bf16 store, bias per row (V^T: row = h*64+hd)
                const float4 bv4 = *(const float4*)(bias + row);
                const float bb[4] = {bv4.x, bv4.y, bv4.z, bv4.w};
#pragma unroll
                for (int r = 0; r < 4; ++r)
                    outb[(size_t)(row + r) * N + col] = f2b(v[r] + bb[r]);
            }
        }
    }
}

// ---------------- causal flash attention v4: S^T formulation, no-max softmax,
// double-buffered K/V (one barrier/iter), XCD-affinity block mapping:
// all 8 sub-blocks of one (b,h) share bid%8 -> same XCD, so its K/V stream
// (0.5 MB) is L2-resident; per-XCD working set 8 bh x 0.5 MB = 4 MB = L2.
// 512 blocks x 4 balanced passes {g, 15-g, 16+g, 31-g} (66 iters/block).
// V layout: Vt[h*64+hd][b*2048+s]  (written by the MODE-3 V^T GEMM).
__global__ __launch_bounds__(256) void attn_kernel(
    const short* __restrict__ Q, const short* __restrict__ K,
    const short* __restrict__ Vt, short* __restrict__ O) {
    const int bid = blockIdx.x;
    const int xcd = bid & 7;
    const int sub = (bid >> 3) & 7;    // gq
    const int grp = bid >> 6;          // 0..7
    const int bh  = grp * 8 + xcd;     // bh % 8 == xcd
    const int h = bh & 15, b = bh >> 4;
    const int gq = sub;
    const int tid = threadIdx.x, wave = tid >> 6, lane = tid & 63;
    const int l16 = lane & 15, quad = lane >> 4;

    __shared__ __align__(16) short Ks[2][64 * 72];
    __shared__ __align__(16) short Vts[2][64 * 72];
    __shared__ __align__(16) short Ps[4][16 * 72];

    const size_t bhoff = (size_t)bh * (2048ull * 64);
    const int srow = tid >> 2;
    const int sseg = (tid & 3) * 16;
    // V^T base for this (b,h): rows h*64+hd, cols b*2048+s
    const short* Vbase = Vt + ((size_t)(h * 64 + srow)) * 8192 + (size_t)b * 2048 + sseg;

    const int qts[4] = {gq, 15 - gq, 16 + gq, 31 - gq};

    for (int pass = 0; pass < 4; ++pass) {
        const int qt = qts[pass];
        const int q0 = qt * 64;
        const int q_lane = q0 + wave * 16 + l16;

        const short* qrow = Q + bhoff + (size_t)q_lane * 64;
        s16x8 bq0 = *(const s16x8*)(qrow + quad * 8);
        s16x8 bq1 = *(const s16x8*)(qrow + 32 + quad * 8);

        f32x4 oacc[4] = {};
        float lsum = 0.0f;

        // prologue: load j=0 tile
        s16x8 k0, k1, v0, v1;
        {
            const short* kg = K + bhoff + (size_t)srow * 64 + sseg;
            k0 = *(const s16x8*)kg;
            k1 = *(const s16x8*)(kg + 8);
            v0 = *(const s16x8*)Vbase;
            v1 = *(const s16x8*)(Vbase + 8);
        }

        for (int j = 0; j <= qt; ++j) {
            const int buf = j & 1;
            // write this tile into its buffer, then ONE barrier.
            *(s16x8*)&Ks[buf][srow * 72 + sseg]      = k0;
            *(s16x8*)&Ks[buf][srow * 72 + sseg + 8]  = k1;
            *(s16x8*)&Vts[buf][srow * 72 + sseg]     = v0;
            *(s16x8*)&Vts[buf][srow * 72 + sseg + 8] = v1;
            __syncthreads();

            // prefetch next tile while computing this one
            if (j < qt) {
                const short* kg = K + bhoff + (size_t)((j + 1) * 64 + srow) * 64 + sseg;
                k0 = *(const s16x8*)kg;
                k1 = *(const s16x8*)(kg + 8);
                const short* vg = Vbase + (j + 1) * 64;
                v0 = *(const s16x8*)vg;
                v1 = *(const s16x8*)(vg + 8);
            }

            // S^T = K·Qᵀ
            f32x4 st[4];
#pragma unroll
            for (int s = 0; s < 4; ++s) {
                s16x8 ak0 = *(const s16x8*)&Ks[buf][(s * 16 + l16) * 72 + quad * 8];
                s16x8 ak1 = *(const s16x8*)&Ks[buf][(s * 16 + l16) * 72 + 32 + quad * 8];
                f32x4 c = {};
                c = mfma16(ak0, bq0, c);
                c = mfma16(ak1, bq1, c);
                st[s] = c;
            }
            // causal mask (diagonal tile only); scale already folded into Q
            if (j == qt) {
#pragma unroll
                for (int s = 0; s < 4; ++s)
#pragma unroll
                    for (int r = 0; r < 4; ++r) {
                        const int t = j * 64 + s * 16 + quad * 4 + r;
                        if (t > q_lane) st[s][r] = -3000.0f;
                    }
            }
            // p = exp2(s), row sum, pack P to LDS
            float rs = 0.0f;
#pragma unroll
            for (int s = 0; s < 4; ++s) {
#pragma unroll
                for (int r = 0; r < 4; ++r) {
                    st[s][r] = exp2f(st[s][r]);
                    rs += st[s][r];
                }
                int2 pw;
                pw.x = pk2(st[s][0], st[s][1]);
                pw.y = pk2(st[s][2], st[s][3]);
                *(int2*)&Ps[wave][l16 * 72 + s * 16 + quad * 4] = pw;
            }
            rs += __shfl_xor(rs, 16);
            rs += __shfl_xor(rs, 32);
            lsum += rs;

            asm volatile("s_waitcnt lgkmcnt(0)" ::: "memory");
            s16x8 ap0 = *(const s16x8*)&Ps[wave][l16 * 72 + quad * 8];
            s16x8 ap1 = *(const s16x8*)&Ps[wave][l16 * 72 + 32 + quad * 8];

            // O += P V
#pragma unroll
            for (int nt = 0; nt < 4; ++nt) {
                s16x8 bv0 = *(const s16x8*)&Vts[buf][(nt * 16 + l16) * 72 + quad * 8];
                s16x8 bv1 = *(const s16x8*)&Vts[buf][(nt * 16 + l16) * 72 + 32 + quad * 8];
                oacc[nt] = mfma16(ap0, bv0, oacc[nt]);
                oacc[nt] = mfma16(ap1, bv1, oacc[nt]);
            }
        }
        __syncthreads();   // all reads done before next pass restages buf0

        // epilogue: O[b, s, h*64+hd] bf16; lsum lives in l16 domain -> shfl
        float inv[4];
#pragma unroll
        for (int r = 0; r < 4; ++r)
            inv[r] = 1.0f / __shfl(lsum, quad * 4 + r, 64);
#pragma unroll
        for (int nt = 0; nt < 4; ++nt)
#pragma unroll
            for (int r = 0; r < 4; ++r) {
                const int row = q0 + wave * 16 + quad * 4 + r;
                O[((size_t)b * 2048 + row) * 1024 + h * 64 + nt * 16 + l16] =
                    f2b(oacc[nt][r] * inv[r]);
            }
    }
}

extern "C" void kernel_launch(void* const* d_in, const int* in_sizes, int n_in,
                              void* d_out, int out_size, void* d_ws, size_t ws_size,
                              hipStream_t stream) {
    const float* x     = (const float*)d_in[0];
    const float* Wq    = (const float*)d_in[1];
    const float* Wk    = (const float*)d_in[2];
    const float* Wv    = (const float*)d_in[3];
    const float* bq    = (const float*)d_in[4];
    const float* bk    = (const float*)d_in[5];
    const float* bv    = (const float*)d_in[6];
    const float* Wo    = (const float*)d_in[7];
    const float* bo    = (const float*)d_in[8];
    const float* W1    = (const float*)d_in[9];
    const float* b1    = (const float*)d_in[10];
    const float* W2    = (const float*)d_in[11];
    const float* b2    = (const float*)d_in[12];
    const float* gamma = (const float*)d_in[13];
    const float* beta  = (const float*)d_in[14];
    float* out = (float*)d_out;

    char* ws = (char*)d_ws;
    size_t off = 0;
    auto alloc = [&](size_t bytes) -> char* {
        char* p = ws + off;
        off += (bytes + 255) & ~(size_t)255;
        return p;
    };
    short* h1    = (short*)alloc(8192ull * 1024 * 2);
    short* btqkv = (short*)alloc(3072ull * 1024 * 2);
    short* btwo  = (short*)alloc(1024ull * 1024 * 2);
    short* btw1  = (short*)alloc(4096ull * 1024 * 2);
    short* btw2  = (short*)alloc(1024ull * 4096 * 2);
    float* bqkv  = (float*)alloc(3072ull * 4);
    short* qkv   = (short*)alloc(2ull * 8192 * 1024 * 2);   // Q,K only
    short* vt    = (short*)alloc(8192ull * 1024 * 2);       // V^T [1024][8192]
    short* aout  = (short*)alloc(8192ull * 1024 * 2);
    float* x2    = (float*)alloc(8192ull * 1024 * 4);
    short* h2    = (short*)alloc(8192ull * 1024 * 2);
    short* m1    = (short*)alloc(8192ull * 4096 * 2);

    // weight prep
    transpose_bf16<<<dim3(2, 32, 16), 256, 0, stream>>>(Wq, btqkv, 1024, 64);
    transpose_bf16<<<dim3(2, 32, 16), 256, 0, stream>>>(Wk, btqkv + 1024ull * 1024, 1024, 64);
    transpose_bf16<<<dim3(2, 32, 16), 256, 0, stream>>>(Wv, btqkv + 2ull * 1024 * 1024, 1024, 64);
    transpose_bf16<<<dim3(32, 32, 1), 256, 0, stream>>>(Wo, btwo, 1024, 1024);
    transpose_bf16<<<dim3(128, 32, 1), 256, 0, stream>>>(W1, btw1, 1024, 4096);
    transpose_bf16<<<dim3(32, 128, 1), 256, 0, stream>>>(W2, btw2, 4096, 1024);
    concat_bias<<<12, 256, 0, stream>>>(bq, bk, bv, bqkv);

    // LN1
    ln_bf16<<<8192, 256, 0, stream>>>(x, gamma, beta, h1);
    // Q,K projection (N=2048, 1024 blocks = 4 exact CU rounds)
    gemm_bf16<0, 0><<<dim3(16, 64), 512, 0, stream>>>(
        h1, btqkv, bqkv, nullptr, nullptr, qkv, 8192, 2048, 1024);
    // V^T = Wv^T * h1^T directly (M=1024, N=8192, 512 blocks = 2 rounds).
    // Eliminates the 4KB-stride 8B V scatter; epilogue is natural coalesced.
    gemm_bf16<3, 0><<<dim3(64, 8), 512, 0, stream>>>(
        btqkv + 2ull * 1024 * 1024, h1, bqkv + 2048, nullptr, nullptr, vt,
        1024, 8192, 1024);
    // attention (XCD-affinity mapping)
    attn_kernel<<<512, 256, 0, stream>>>(
        qkv, qkv + 8192ull * 1024, vt, aout);
    // Wo + residual -> x2 (f32)
    gemm_bf16<1, 0><<<dim3(8, 64), 512, 0, stream>>>(
        aout, btwo, bo, x, x2, nullptr, 8192, 1024, 1024);
    // LN2
    ln_bf16<<<8192, 256, 0, stream>>>(x2, gamma, beta, h2);
    // MLP1 + GELU
    gemm_bf16<2, 0><<<dim3(32, 64), 512, 0, stream>>>(
        h2, btw1, b1, nullptr, nullptr, m1, 8192, 4096, 1024);
    // MLP2 + residual -> out (f32), M-band swizzle (R8-measured best)
    gemm_bf16<1, 1><<<dim3(8, 64), 512, 0, stream>>>(
        m1, btw2, b2, x2, out, nullptr, 8192, 1024, 4096);
}

// Round 7
// 511.039 us; speedup vs baseline: 1.3686x; 1.0180x over previous
//
#include <hip/hip_runtime.h>
#include <hip/hip_bf16.h>

typedef __bf16  bf16x8 __attribute__((ext_vector_type(8)));
typedef float   f32x4  __attribute__((ext_vector_type(4)));
typedef short   s16x8  __attribute__((ext_vector_type(8)));

typedef const __attribute__((address_space(1))) void g_void;
typedef __attribute__((address_space(3))) void l_void;

__device__ __forceinline__ short f2b(float x) {
    __hip_bfloat16 h = __float2bfloat16(x);
    return __builtin_bit_cast(short, h);
}

// pack two floats to bf16 pair in one int (lo | hi<<16)
__device__ __forceinline__ int pk2(float lo, float hi) {
    return (int)(unsigned short)f2b(lo) | ((int)f2b(hi) << 16);
}

// fast GELU: tanh form via hardware exp2. gelu(v) = v*t/(t+1),
// t = exp2(K1*(v + 0.044715 v^3)), K1 = 2*log2(e)*0.7978845608.
__device__ __forceinline__ float fast_gelu(float v) {
    const float a = fminf(2.3022082f * (v + 0.044715f * v * v * v), 126.0f);
    const float t = exp2f(a);
    return v * t / (t + 1.0f);
}

__device__ __forceinline__ f32x4 mfma16(s16x8 a, s16x8 b, f32x4 c) {
    return __builtin_amdgcn_mfma_f32_16x16x32_bf16(
        __builtin_bit_cast(bf16x8, a), __builtin_bit_cast(bf16x8, b), c, 0, 0, 0);
}

// ---------------- transpose + fp32 -> bf16 :  src [R,C] f32 -> dst [C,R] bf16
__global__ __launch_bounds__(256) void transpose_bf16(
    const float* __restrict__ src, short* __restrict__ dst, int R, int C) {
    __shared__ float tile[32][33];
    src += (size_t)blockIdx.z * R * C;
    dst += (size_t)blockIdx.z * R * C;
    const int c0 = blockIdx.x * 32, r0 = blockIdx.y * 32;
    const int tx = threadIdx.x & 31, ty = threadIdx.x >> 5;
#pragma unroll
    for (int i = 0; i < 32; i += 8)
        tile[ty + i][tx] = src[(size_t)(r0 + ty + i) * C + c0 + tx];
    __syncthreads();
#pragma unroll
    for (int i = 0; i < 32; i += 8)
        dst[(size_t)(c0 + ty + i) * R + r0 + tx] = f2b(tile[tx][ty + i]);
}

// ---------------- concat q/k/v bias into [3072] f32
__global__ __launch_bounds__(256) void concat_bias(
    const float* __restrict__ bq, const float* __restrict__ bk,
    const float* __restrict__ bv, float* __restrict__ o) {
    int i = blockIdx.x * 256 + threadIdx.x;
    if (i < 1024)      o[i] = bq[i];
    else if (i < 2048) o[i] = bk[i - 1024];
    else if (i < 3072) o[i] = bv[i - 2048];
}

// ---------------- LayerNorm (D=1024) f32 in -> bf16 out. 1 block/row, 256 thr
__global__ __launch_bounds__(256) void ln_bf16(
    const float* __restrict__ x, const float* __restrict__ gamma,
    const float* __restrict__ beta, short* __restrict__ out) {
    __shared__ float red[8];
    const int row = blockIdx.x, tid = threadIdx.x;
    const float4 v = *(const float4*)(x + (size_t)row * 1024 + tid * 4);
    float s = v.x + v.y + v.z + v.w;
    float q = v.x * v.x + v.y * v.y + v.z * v.z + v.w * v.w;
#pragma unroll
    for (int off = 32; off > 0; off >>= 1) {
        s += __shfl_xor(s, off);
        q += __shfl_xor(q, off);
    }
    if ((tid & 63) == 0) { red[(tid >> 6) * 2] = s; red[(tid >> 6) * 2 + 1] = q; }
    __syncthreads();
    s = red[0] + red[2] + red[4] + red[6];
    q = red[1] + red[3] + red[5] + red[7];
    const float mu = s * (1.0f / 1024.0f);
    const float var = q * (1.0f / 1024.0f) - mu * mu;
    const float rs = rsqrtf(var + 1e-5f);
    const float4 g  = *(const float4*)(gamma + tid * 4);
    const float4 bt = *(const float4*)(beta + tid * 4);
    short4 o;
    o.x = f2b((v.x - mu) * rs * g.x + bt.x);
    o.y = f2b((v.y - mu) * rs * g.y + bt.y);
    o.z = f2b((v.z - mu) * rs * g.z + bt.z);
    o.w = f2b((v.w - mu) * rs * g.w + bt.w);
    *(short4*)(out + (size_t)row * 1024 + tid * 4) = o;
}

// ---------------- bf16 MFMA GEMM: C[M,N] = A[M,K] * Bt[N,K]^T (+ epilogue)
// 128x128 tile, BK=64 as two 32-K panels, 512 threads (8 waves).
// SWZ 0 (N-band): each XCD owns an N-band whose B-slice stays L2-resident.
// SWZ 1 (M-band): each XCD owns a contiguous M-band (best for MLP2, R8).
// MODE 0: QKV scatter: Q (pre-scaled by 1/8*log2e), K -> [2][B,H,S,HD];
//         V -> vt [B,H,HD,S]
// MODE 1: out f32 = acc + bias[col] + resid[row*N+col]
// MODE 2: out bf16 = fast_gelu(acc + bias[col])
template <int MODE, int SWZ>
__global__ __launch_bounds__(512) void gemm_bf16(
    const short* __restrict__ A, const short* __restrict__ Bt,
    const float* __restrict__ bias, const float* __restrict__ resid,
    float* __restrict__ outf, short* __restrict__ outb, short* __restrict__ vt,
    int M, int N, int K) {
    __shared__ __align__(16) short As[2 * 128 * 32];
    __shared__ __align__(16) short Bs[2 * 128 * 32];

    const int tid = threadIdx.x;
    const int wave = tid >> 6, lane = tid & 63;
    const int l16 = lane & 15, quad = lane >> 4;
    const int wm = wave & 3, wn = wave >> 2;   // 4 row-strips x 2 col-strips
    const int gx = gridDim.x;
    const int g = blockIdx.y * gx + blockIdx.x;
    const int xcd = g & 7, s = g >> 3;
    int m0, n0;
    if (SWZ == 0) {                            // N-band (requires gx % 8 == 0)
        const int nband = gx >> 3;
        const int sm = s / nband;
        const int sn = s - sm * nband;
        m0 = sm * 128;
        n0 = (xcd * nband + sn) * 128;
    } else {                                   // M-band (requires gy % 8 == 0)
        const int mband = gridDim.y >> 3;
        const int sm = s / gx;
        m0 = (xcd * mband + sm) * 128;
        n0 = (s - sm * gx) * 128;
    }
    const int lrow = lane >> 2;        // 0..15
    const int lcol = (lane & 3) * 8;   // 16B chunk within a 32-elem panel row

    f32x4 acc[2][4] = {};

    for (int kk = 0; kk < K; kk += 64) {
#pragma unroll
        for (int p = 0; p < 2; ++p) {        // 32-K panel
            const int r = wave * 16 + lrow;  // 8 waves x 16 rows = 128
            const short* ga = A + (size_t)(m0 + r) * K + kk + p * 32 + lcol;
            short* la = &As[p * 4096 + wave * 512];
            __builtin_amdgcn_global_load_lds((g_void*)ga, (l_void*)la, 16, 0, 0);
            const short* gb = Bt + (size_t)(n0 + r) * K + kk + p * 32 + lcol;
            short* lb = &Bs[p * 4096 + wave * 512];
            __builtin_amdgcn_global_load_lds((g_void*)gb, (l_void*)lb, 16, 0, 0);
        }
        __syncthreads();
#pragma unroll
        for (int p = 0; p < 2; ++p) {
            s16x8 a[2], b[4];
#pragma unroll
            for (int t = 0; t < 2; ++t)
                a[t] = *(const s16x8*)&As[p * 4096 + (wm * 32 + t * 16 + l16) * 32 + quad * 8];
#pragma unroll
            for (int t = 0; t < 4; ++t)
                b[t] = *(const s16x8*)&Bs[p * 4096 + (wn * 64 + t * 16 + l16) * 32 + quad * 8];
#pragma unroll
            for (int mt = 0; mt < 2; ++mt)
#pragma unroll
                for (int nt = 0; nt < 4; ++nt)
                    acc[mt][nt] = mfma16(a[mt], b[nt], acc[mt][nt]);
        }
        __syncthreads();
    }

#pragma unroll
    for (int mt = 0; mt < 2; ++mt) {
#pragma unroll
        for (int nt = 0; nt < 4; ++nt) {
            const int row = m0 + wm * 32 + mt * 16 + quad * 4;   // + r
            const int col = n0 + wn * 64 + nt * 16 + l16;
            const float bc = bias[col];
            float v[4];
#pragma unroll
            for (int r = 0; r < 4; ++r) v[r] = acc[mt][nt][r] + bc;

            if (MODE == 0) {
                const int sel = col >> 10, within = col & 1023;
                const int h = within >> 6, hd = within & 63;
                const size_t bidx = (size_t)row >> 11, sp = row & 2047;
                if (sel == 0) {
                    // fold softmax scale (1/sqrt(64) * log2e) into Q
#pragma unroll
                    for (int r = 0; r < 4; ++r) v[r] *= 0.18033688011112042f;
                }
                if (sel < 2) {
#pragma unroll
                    for (int r = 0; r < 4; ++r)
                        outb[(size_t)sel * (8192ull * 1024) +
                             ((bidx * 16 + h) * 2048 + sp + r) * 64 + hd] = f2b(v[r]);
                } else {
                    short4 o4;
                    o4.x = f2b(v[0]); o4.y = f2b(v[1]);
                    o4.z = f2b(v[2]); o4.w = f2b(v[3]);
                    *(short4*)&vt[((bidx * 16 + h) * 64 + hd) * 2048 + sp] = o4;
                }
            } else if (MODE == 1) {
#pragma unroll
                for (int r = 0; r < 4; ++r) {
                    const size_t rr = (size_t)(row + r);
                    outf[rr * N + col] = v[r] + resid[rr * N + col];
                }
            } else {
#pragma unroll
                for (int r = 0; r < 4; ++r)
                    outb[(size_t)(row + r) * N + col] = f2b(fast_gelu(v[r]));
            }
        }
    }
}

// ---------------- causal flash attention v5: S^T formulation, no-max softmax,
// double-buffered K/V (one barrier/iter), XCD-affinity block mapping.
// OCCUPANCY RESTRUCTURE (R6->R7): 1024 blocks x 2 balanced passes {gq, 31-gq}
// (33 iters/block exactly) instead of 512 x 4. 4 blocks/CU scheduled, 3
// co-resident (LDS 46KB x 3 = 138KB < 160KB) -> 12 waves/CU so independent
// blocks overlap softmax-VALU with MFMA. Per-XCD K/V working set unchanged:
// bh = grp*8 + (bid&7) keeps bh%8 == xcd -> 8 bh x 0.5MB = 4MB = L2.
__global__ __launch_bounds__(256) void attn_kernel(
    const short* __restrict__ Q, const short* __restrict__ K,
    const short* __restrict__ Vt, short* __restrict__ O) {
    const int bid = blockIdx.x;
    const int xcd = bid & 7;
    const int gq  = (bid >> 3) & 15;   // 0..15
    const int grp = bid >> 7;          // 0..7
    const int bh  = grp * 8 + xcd;     // bh % 8 == xcd
    const int h = bh & 15, b = bh >> 4;
    const int tid = threadIdx.x, wave = tid >> 6, lane = tid & 63;
    const int l16 = lane & 15, quad = lane >> 4;

    __shared__ __align__(16) short Ks[2][64 * 72];
    __shared__ __align__(16) short Vts[2][64 * 72];
    __shared__ __align__(16) short Ps[4][16 * 72];

    const size_t bhoff = (size_t)bh * (2048ull * 64);
    const int srow = tid >> 2;
    const int sseg = (tid & 3) * 16;

    const int qts[2] = {gq, 31 - gq};  // (gq+1) + (32-gq) = 33 iters/block

    for (int pass = 0; pass < 2; ++pass) {
        const int qt = qts[pass];
        const int q0 = qt * 64;
        const int q_lane = q0 + wave * 16 + l16;

        const short* qrow = Q + bhoff + (size_t)q_lane * 64;
        s16x8 bq0 = *(const s16x8*)(qrow + quad * 8);
        s16x8 bq1 = *(const s16x8*)(qrow + 32 + quad * 8);

        f32x4 oacc[4] = {};
        float lsum = 0.0f;

        // prologue: load j=0 tile
        s16x8 k0, k1, v0, v1;
        {
            const short* kg = K + bhoff + (size_t)srow * 64 + sseg;
            k0 = *(const s16x8*)kg;
            k1 = *(const s16x8*)(kg + 8);
            const short* vg = Vt + bhoff + (size_t)srow * 2048 + sseg;
            v0 = *(const s16x8*)vg;
            v1 = *(const s16x8*)(vg + 8);
        }

        for (int j = 0; j <= qt; ++j) {
            const int buf = j & 1;
            // write this tile into its buffer, then ONE barrier.
            *(s16x8*)&Ks[buf][srow * 72 + sseg]      = k0;
            *(s16x8*)&Ks[buf][srow * 72 + sseg + 8]  = k1;
            *(s16x8*)&Vts[buf][srow * 72 + sseg]     = v0;
            *(s16x8*)&Vts[buf][srow * 72 + sseg + 8] = v1;
            __syncthreads();

            // prefetch next tile while computing this one
            if (j < qt) {
                const short* kg = K + bhoff + (size_t)((j + 1) * 64 + srow) * 64 + sseg;
                k0 = *(const s16x8*)kg;
                k1 = *(const s16x8*)(kg + 8);
                const short* vg = Vt + bhoff + (size_t)srow * 2048 + (j + 1) * 64 + sseg;
                v0 = *(const s16x8*)vg;
                v1 = *(const s16x8*)(vg + 8);
            }

            // S^T = K·Qᵀ: st[s][r] = S[q=l16][t = j*64 + s*16 + quad*4 + r]
            f32x4 st[4];
#pragma unroll
            for (int s = 0; s < 4; ++s) {
                s16x8 ak0 = *(const s16x8*)&Ks[buf][(s * 16 + l16) * 72 + quad * 8];
                s16x8 ak1 = *(const s16x8*)&Ks[buf][(s * 16 + l16) * 72 + 32 + quad * 8];
                f32x4 c = {};
                c = mfma16(ak0, bq0, c);
                c = mfma16(ak1, bq1, c);
                st[s] = c;
            }
            // causal mask (diagonal tile only); scale already folded into Q
            if (j == qt) {
#pragma unroll
                for (int s = 0; s < 4; ++s)
#pragma unroll
                    for (int r = 0; r < 4; ++r) {
                        const int t = j * 64 + s * 16 + quad * 4 + r;
                        if (t > q_lane) st[s][r] = -3000.0f;
                    }
            }
            // p = exp2(s)  (no max subtraction), row sum, pack P to LDS
            float rs = 0.0f;
#pragma unroll
            for (int s = 0; s < 4; ++s) {
#pragma unroll
                for (int r = 0; r < 4; ++r) {
                    st[s][r] = exp2f(st[s][r]);
                    rs += st[s][r];
                }
                int2 pw;
                pw.x = pk2(st[s][0], st[s][1]);
                pw.y = pk2(st[s][2], st[s][3]);
                *(int2*)&Ps[wave][l16 * 72 + s * 16 + quad * 4] = pw;
            }
            rs += __shfl_xor(rs, 16);
            rs += __shfl_xor(rs, 32);
            lsum += rs;

            asm volatile("s_waitcnt lgkmcnt(0)" ::: "memory");
            s16x8 ap0 = *(const s16x8*)&Ps[wave][l16 * 72 + quad * 8];
            s16x8 ap1 = *(const s16x8*)&Ps[wave][l16 * 72 + 32 + quad * 8];

            // O += P V
#pragma unroll
            for (int nt = 0; nt < 4; ++nt) {
                s16x8 bv0 = *(const s16x8*)&Vts[buf][(nt * 16 + l16) * 72 + quad * 8];
                s16x8 bv1 = *(const s16x8*)&Vts[buf][(nt * 16 + l16) * 72 + 32 + quad * 8];
                oacc[nt] = mfma16(ap0, bv0, oacc[nt]);
                oacc[nt] = mfma16(ap1, bv1, oacc[nt]);
            }
        }
        __syncthreads();   // all reads done before next pass restages buf0

        // epilogue: O[b, s, h*64+hd] bf16; lsum lives in l16 domain -> shfl
        float inv[4];
#pragma unroll
        for (int r = 0; r < 4; ++r)
            inv[r] = 1.0f / __shfl(lsum, quad * 4 + r, 64);
#pragma unroll
        for (int nt = 0; nt < 4; ++nt)
#pragma unroll
            for (int r = 0; r < 4; ++r) {
                const int row = q0 + wave * 16 + quad * 4 + r;
                O[((size_t)b * 2048 + row) * 1024 + h * 64 + nt * 16 + l16] =
                    f2b(oacc[nt][r] * inv[r]);
            }
    }
}

extern "C" void kernel_launch(void* const* d_in, const int* in_sizes, int n_in,
                              void* d_out, int out_size, void* d_ws, size_t ws_size,
                              hipStream_t stream) {
    const float* x     = (const float*)d_in[0];
    const float* Wq    = (const float*)d_in[1];
    const float* Wk    = (const float*)d_in[2];
    const float* Wv    = (const float*)d_in[3];
    const float* bq    = (const float*)d_in[4];
    const float* bk    = (const float*)d_in[5];
    const float* bv    = (const float*)d_in[6];
    const float* Wo    = (const float*)d_in[7];
    const float* bo    = (const float*)d_in[8];
    const float* W1    = (const float*)d_in[9];
    const float* b1    = (const float*)d_in[10];
    const float* W2    = (const float*)d_in[11];
    const float* b2    = (const float*)d_in[12];
    const float* gamma = (const float*)d_in[13];
    const float* beta  = (const float*)d_in[14];
    float* out = (float*)d_out;

    char* ws = (char*)d_ws;
    size_t off = 0;
    auto alloc = [&](size_t bytes) -> char* {
        char* p = ws + off;
        off += (bytes + 255) & ~(size_t)255;
        return p;
    };
    short* h1    = (short*)alloc(8192ull * 1024 * 2);
    short* btqkv = (short*)alloc(3072ull * 1024 * 2);
    short* btwo  = (short*)alloc(1024ull * 1024 * 2);
    short* btw1  = (short*)alloc(4096ull * 1024 * 2);
    short* btw2  = (short*)alloc(1024ull * 4096 * 2);
    float* bqkv  = (float*)alloc(3072ull * 4);
    short* qkv   = (short*)alloc(2ull * 8192 * 1024 * 2);   // Q,K only
    short* vt    = (short*)alloc(8192ull * 1024 * 2);       // V pre-transposed
    short* aout  = (short*)alloc(8192ull * 1024 * 2);
    float* x2    = (float*)alloc(8192ull * 1024 * 4);
    short* h2    = (short*)alloc(8192ull * 1024 * 2);
    short* m1    = (short*)alloc(8192ull * 4096 * 2);

    // weight prep
    transpose_bf16<<<dim3(2, 32, 16), 256, 0, stream>>>(Wq, btqkv, 1024, 64);
    transpose_bf16<<<dim3(2, 32, 16), 256, 0, stream>>>(Wk, btqkv + 1024ull * 1024, 1024, 64);
    transpose_bf16<<<dim3(2, 32, 16), 256, 0, stream>>>(Wv, btqkv + 2ull * 1024 * 1024, 1024, 64);
    transpose_bf16<<<dim3(32, 32, 1), 256, 0, stream>>>(Wo, btwo, 1024, 1024);
    transpose_bf16<<<dim3(128, 32, 1), 256, 0, stream>>>(W1, btw1, 1024, 4096);
    transpose_bf16<<<dim3(32, 128, 1), 256, 0, stream>>>(W2, btw2, 4096, 1024);
    concat_bias<<<12, 256, 0, stream>>>(bq, bk, bv, bqkv);

    // LN1
    ln_bf16<<<8192, 256, 0, stream>>>(x, gamma, beta, h1);
    // QKV projection (V written directly transposed into vt; Q pre-scaled)
    gemm_bf16<0, 0><<<dim3(24, 64), 512, 0, stream>>>(
        h1, btqkv, bqkv, nullptr, nullptr, qkv, vt, 8192, 3072, 1024);
    // attention: 1024 blocks x 2 balanced passes (occupancy 2->3 blocks/CU)
    attn_kernel<<<1024, 256, 0, stream>>>(
        qkv, qkv + 8192ull * 1024, vt, aout);
    // Wo + residual -> x2 (f32)
    gemm_bf16<1, 0><<<dim3(8, 64), 512, 0, stream>>>(
        aout, btwo, bo, x, x2, nullptr, nullptr, 8192, 1024, 1024);
    // LN2
    ln_bf16<<<8192, 256, 0, stream>>>(x2, gamma, beta, h2);
    // MLP1 + GELU (fast tanh-form, exp2-based)
    gemm_bf16<2, 0><<<dim3(32, 64), 512, 0, stream>>>(
        h2, btw1, b1, nullptr, nullptr, m1, nullptr, 8192, 4096, 1024);
    // MLP2 + residual -> out (f32), M-band swizzle (R8-measured best)
    gemm_bf16<1, 1><<<dim3(8, 64), 512, 0, stream>>>(
        m1, btw2, b2, x2, out, nullptr, nullptr, 8192, 1024, 4096);
}